// Round 12
// baseline (345.372 us; speedup 1.0000x reference)
//
#include <hip/hip_runtime.h>
#include <hip/hip_fp16.h>

// ---------------------------------------------------------------------------
// ServiceGNN: 2-layer single-head GAT (+self-loops, segment softmax) + FC head
// N=50000, E=800000 (+N self loops), D_in=D_h=128, D_out=57.
// R12 = bisect of R11's fail: KEEP count-as-prelude in gemm1 (fire-and-forget
// atomics hidden under GEMM); REVERT agg to R10's verified 4B/lane x8-unroll
// version (R11's 16-lane/edge rewrite with divergent-shfl tail is the prime
// miscompile suspect).
// ---------------------------------------------------------------------------

#define NEG_SLOPE 0.2f

struct __align__(8) half4_t { __half2 a, b; };

// ---------------- int64-vs-int32 edge_index probe ----------------
__global__ void probe_i64_kernel(const int* __restrict__ ei, int E, int* __restrict__ flag)
{
    int lane = threadIdx.x;              // blockDim = 64
    int v = 0;
    int lim = (E < 256) ? E : 256;
    for (int t = lane; t < lim; t += 64) v |= ei[2 * t + 1];
    #pragma unroll
    for (int o = 32; o >= 1; o >>= 1) v |= __shfl_xor(v, o);
    if (lane == 0) flag[0] = (v == 0) ? 1 : 0;
}

// ---------------- gemm1 (+alphas) with count prelude ----------------
// Every block first issues its slice of degree-count atomics WITHOUT using
// the results (fire-and-forget; no wave stall) — they drain during the GEMM.
__global__ __launch_bounds__(256) void gemm1_count_kernel(
    const float* __restrict__ X, const float* __restrict__ W,
    const float* __restrict__ asv, const float* __restrict__ adv,
    __half* __restrict__ H16, float* __restrict__ As, float* __restrict__ Ad, int n,
    const int* __restrict__ ei, int E, const int* __restrict__ flag,
    int* __restrict__ deg)
{
    __shared__ float Wl[64 * 128];       // 32 KB

    {   // ---- count prelude: 4 edges/thread, grid-stride ----
        int is64 = flag[0];
        int gid = blockIdx.x * 256 + threadIdx.x;
        int stride = gridDim.x * 256 * 4;
        for (int base = gid * 4; base < E; base += stride) {
            if (base + 4 <= E) {
                int d0, d1, d2, d3;
                if (is64) {
                    const int4* q = (const int4*)ei;   // int4 = 2 int64
                    int4 a = q[(E + base) >> 1];
                    int4 b = q[((E + base) >> 1) + 1];
                    d0 = a.x; d1 = a.z; d2 = b.x; d3 = b.z;
                } else {
                    int4 a = *(const int4*)(ei + E + base);
                    d0 = a.x; d1 = a.y; d2 = a.z; d3 = a.w;
                }
                atomicAdd(&deg[d0], 1); atomicAdd(&deg[d1], 1);
                atomicAdd(&deg[d2], 1); atomicAdd(&deg[d3], 1);
            } else {
                for (int u = 0; u < E - base; ++u) {
                    int dd = is64 ? ei[2 * (E + base + u)] : ei[E + base + u];
                    atomicAdd(&deg[dd], 1);
                }
            }
        }
    }

    // ---- gemm: 32 rows x 128 cols per block, K split in two 64 phases ----
    int tid = threadIdx.x;
    int cg = tid & 15, rg = tid >> 4;
    int row0 = blockIdx.x * 32;
    int r0 = row0 + rg * 2, r1 = r0 + 1;
    int rc0 = (r0 < n) ? r0 : (n - 1);
    int rc1 = (r1 < n) ? r1 : (n - 1);

    float acc[2][8];
    #pragma unroll
    for (int i = 0; i < 2; ++i)
        #pragma unroll
        for (int c = 0; c < 8; ++c) acc[i][c] = 0.f;

    const float4* Wl4 = (const float4*)Wl;

    #pragma unroll
    for (int p = 0; p < 2; ++p) {
        {
            const float4* W4 = (const float4*)(W + p * 64 * 128);
            float4* Wl4w = (float4*)Wl;
            #pragma unroll
            for (int t = 0; t < 8; ++t) Wl4w[tid + t * 256] = W4[tid + t * 256];
        }
        __syncthreads();

        const float* X0 = X + (size_t)rc0 * 128 + p * 64;
        const float* X1 = X + (size_t)rc1 * 128 + p * 64;
        for (int k = 0; k < 64; k += 4) {
            float4 xa = *(const float4*)(X0 + k);
            float4 xb = *(const float4*)(X1 + k);
            #pragma unroll
            for (int kk = 0; kk < 4; ++kk) {
                float4 wA = Wl4[(k + kk) * 32 + cg];
                float4 wB = Wl4[(k + kk) * 32 + 16 + cg];
                float x0s = (kk == 0) ? xa.x : (kk == 1) ? xa.y : (kk == 2) ? xa.z : xa.w;
                float x1s = (kk == 0) ? xb.x : (kk == 1) ? xb.y : (kk == 2) ? xb.z : xb.w;
                acc[0][0] += x0s * wA.x; acc[0][1] += x0s * wA.y;
                acc[0][2] += x0s * wA.z; acc[0][3] += x0s * wA.w;
                acc[0][4] += x0s * wB.x; acc[0][5] += x0s * wB.y;
                acc[0][6] += x0s * wB.z; acc[0][7] += x0s * wB.w;
                acc[1][0] += x1s * wA.x; acc[1][1] += x1s * wA.y;
                acc[1][2] += x1s * wA.z; acc[1][3] += x1s * wA.w;
                acc[1][4] += x1s * wB.x; acc[1][5] += x1s * wB.y;
                acc[1][6] += x1s * wB.z; acc[1][7] += x1s * wB.w;
            }
        }
        __syncthreads();
    }

    float4 asA = *(const float4*)(asv + cg * 4);
    float4 asB = *(const float4*)(asv + 64 + cg * 4);
    float4 adA = *(const float4*)(adv + cg * 4);
    float4 adB = *(const float4*)(adv + 64 + cg * 4);

    #pragma unroll
    for (int i = 0; i < 2; ++i) {
        int r = r0 + i;
        float ps = acc[i][0] * asA.x + acc[i][1] * asA.y + acc[i][2] * asA.z + acc[i][3] * asA.w
                 + acc[i][4] * asB.x + acc[i][5] * asB.y + acc[i][6] * asB.z + acc[i][7] * asB.w;
        float pd = acc[i][0] * adA.x + acc[i][1] * adA.y + acc[i][2] * adA.z + acc[i][3] * adA.w
                 + acc[i][4] * adB.x + acc[i][5] * adB.y + acc[i][6] * adB.z + acc[i][7] * adB.w;
        #pragma unroll
        for (int mask = 8; mask >= 1; mask >>= 1) {
            ps += __shfl_xor(ps, mask);
            pd += __shfl_xor(pd, mask);
        }
        if (r < n) {
            half4_t hlo, hhi;
            hlo.a = __floats2half2_rn(acc[i][0], acc[i][1]);
            hlo.b = __floats2half2_rn(acc[i][2], acc[i][3]);
            hhi.a = __floats2half2_rn(acc[i][4], acc[i][5]);
            hhi.b = __floats2half2_rn(acc[i][6], acc[i][7]);
            *(half4_t*)(H16 + (size_t)r * 128 + cg * 4)      = hlo;
            *(half4_t*)(H16 + (size_t)r * 128 + 64 + cg * 4) = hhi;
            if (cg == 0) { As[r] = ps; Ad[r] = pd; }
        }
    }
}

// scan pass 1: per-1024-chunk inclusive scan of (deg[i] + 1 self-loop).
__global__ __launch_bounds__(1024) void scan1_kernel(
    const int* __restrict__ deg, int* __restrict__ rowptr,
    int* __restrict__ csum, int n)
{
    __shared__ int wsum[16];
    int b = blockIdx.x, tid = threadIdx.x;
    int lane = tid & 63, wv = tid >> 6;
    int i = b * 1024 + tid;
    int v = (i < n) ? (deg[i] + 1) : 0;  // +1 = self-loop
    int s = v;
    #pragma unroll
    for (int off = 1; off < 64; off <<= 1) {
        int t = __shfl_up(s, off);
        if (lane >= off) s += t;
    }
    if (lane == 63) wsum[wv] = s;
    __syncthreads();
    if (wv == 0) {
        int ws = (lane < 16) ? wsum[lane] : 0;
        #pragma unroll
        for (int off = 1; off < 16; off <<= 1) {
            int t = __shfl_up(ws, off);
            if (lane >= off) ws += t;
        }
        if (lane < 16) wsum[lane] = ws;
    }
    __syncthreads();
    int woff = (wv == 0) ? 0 : wsum[wv - 1];
    int incl = woff + s;
    if (i < n) rowptr[i + 1] = incl;
    if (tid == 1023) csum[b] = incl;
    if (b == 0 && tid == 0) rowptr[0] = 0;
}

// scan pass 2: one wave scans the <=64 chunk totals (inclusive).
__global__ void scan2_kernel(int* __restrict__ csum, int nb)
{
    int lane = threadIdx.x;              // blockDim = 64
    int v = (lane < nb) ? csum[lane] : 0;
    #pragma unroll
    for (int off = 1; off < 64; off <<= 1) {
        int t = __shfl_up(v, off);
        if (lane >= off) v += t;
    }
    if (lane < nb) csum[lane] = v;
}

// scan pass 3: add chunk base to chunks 1..nb-1.
__global__ __launch_bounds__(1024) void scan3_kernel(
    const int* __restrict__ csum, int* __restrict__ rowptr, int n)
{
    int b = blockIdx.x + 1;
    int i = b * 1024 + threadIdx.x;
    if (i < n) rowptr[i + 1] += csum[b - 1];
}

// scatter: 4 edges/lane (int4 loads); edges fill slots deg-1..0 of each row
// via atomicSub; self-loop goes to the LAST slot (rowptr[d+1]-1) directly.
__global__ __launch_bounds__(256) void scatter_kernel(
    const int* __restrict__ ei, int E, int n,
    const int* __restrict__ flag,
    const int* __restrict__ rowptr, int* __restrict__ deg, int* __restrict__ col)
{
    int is64 = flag[0];
    int quarter = (E + 3) >> 2;
    int iq = blockIdx.x * blockDim.x + threadIdx.x;
    if (iq < quarter) {
        int base = iq * 4;
        int s[4], d[4];
        int cnt;
        if (base + 4 <= E) {
            cnt = 4;
            if (is64) {
                const int4* q = (const int4*)ei;
                int4 sa = q[base >> 1];
                int4 sb = q[(base >> 1) + 1];
                int4 da = q[(E + base) >> 1];
                int4 db = q[((E + base) >> 1) + 1];
                s[0] = sa.x; s[1] = sa.z; s[2] = sb.x; s[3] = sb.z;
                d[0] = da.x; d[1] = da.z; d[2] = db.x; d[3] = db.z;
            } else {
                int4 sa = *(const int4*)(ei + base);
                int4 da = *(const int4*)(ei + E + base);
                s[0] = sa.x; s[1] = sa.y; s[2] = sa.z; s[3] = sa.w;
                d[0] = da.x; d[1] = da.y; d[2] = da.z; d[3] = da.w;
            }
        } else {
            cnt = E - base;
            for (int u = 0; u < cnt; ++u) {
                if (is64) { s[u] = ei[2 * (base + u)]; d[u] = ei[2 * (E + base + u)]; }
                else      { s[u] = ei[base + u];       d[u] = ei[E + base + u]; }
            }
        }
        #pragma unroll
        for (int u = 0; u < 4; ++u) {
            if (u < cnt) {
                int pos = atomicSub(&deg[d[u]], 1) - 1;
                col[rowptr[d[u]] + pos] = s[u];
            }
        }
    } else {
        int dd = iq - quarter;               // self-loop writes
        if (dd < n) col[rowptr[dd + 1] - 1] = dd;
    }
}

// ---------------- standalone GEMM (layer 2) with fused alpha dots ----------
__global__ __launch_bounds__(256) void gemm_h_kernel(
    const float* __restrict__ X, const float* __restrict__ W,
    const float* __restrict__ asv, const float* __restrict__ adv,
    __half* __restrict__ H16, float* __restrict__ As, float* __restrict__ Ad, int n)
{
    __shared__ float Wl[64 * 128];       // 32 KB
    int tid = threadIdx.x;
    int cg = tid & 15, rg = tid >> 4;
    int row0 = blockIdx.x * 32;
    int r0 = row0 + rg * 2, r1 = r0 + 1;
    int rc0 = (r0 < n) ? r0 : (n - 1);
    int rc1 = (r1 < n) ? r1 : (n - 1);

    float acc[2][8];
    #pragma unroll
    for (int i = 0; i < 2; ++i)
        #pragma unroll
        for (int c = 0; c < 8; ++c) acc[i][c] = 0.f;

    const float4* Wl4 = (const float4*)Wl;

    #pragma unroll
    for (int p = 0; p < 2; ++p) {
        {
            const float4* W4 = (const float4*)(W + p * 64 * 128);
            float4* Wl4w = (float4*)Wl;
            #pragma unroll
            for (int t = 0; t < 8; ++t) Wl4w[tid + t * 256] = W4[tid + t * 256];
        }
        __syncthreads();

        const float* X0 = X + (size_t)rc0 * 128 + p * 64;
        const float* X1 = X + (size_t)rc1 * 128 + p * 64;
        for (int k = 0; k < 64; k += 4) {
            float4 xa = *(const float4*)(X0 + k);
            float4 xb = *(const float4*)(X1 + k);
            #pragma unroll
            for (int kk = 0; kk < 4; ++kk) {
                float4 wA = Wl4[(k + kk) * 32 + cg];
                float4 wB = Wl4[(k + kk) * 32 + 16 + cg];
                float x0s = (kk == 0) ? xa.x : (kk == 1) ? xa.y : (kk == 2) ? xa.z : xa.w;
                float x1s = (kk == 0) ? xb.x : (kk == 1) ? xb.y : (kk == 2) ? xb.z : xb.w;
                acc[0][0] += x0s * wA.x; acc[0][1] += x0s * wA.y;
                acc[0][2] += x0s * wA.z; acc[0][3] += x0s * wA.w;
                acc[0][4] += x0s * wB.x; acc[0][5] += x0s * wB.y;
                acc[0][6] += x0s * wB.z; acc[0][7] += x0s * wB.w;
                acc[1][0] += x1s * wA.x; acc[1][1] += x1s * wA.y;
                acc[1][2] += x1s * wA.z; acc[1][3] += x1s * wA.w;
                acc[1][4] += x1s * wB.x; acc[1][5] += x1s * wB.y;
                acc[1][6] += x1s * wB.z; acc[1][7] += x1s * wB.w;
            }
        }
        __syncthreads();
    }

    float4 asA = *(const float4*)(asv + cg * 4);
    float4 asB = *(const float4*)(asv + 64 + cg * 4);
    float4 adA = *(const float4*)(adv + cg * 4);
    float4 adB = *(const float4*)(adv + 64 + cg * 4);

    #pragma unroll
    for (int i = 0; i < 2; ++i) {
        int r = r0 + i;
        float ps = acc[i][0] * asA.x + acc[i][1] * asA.y + acc[i][2] * asA.z + acc[i][3] * asA.w
                 + acc[i][4] * asB.x + acc[i][5] * asB.y + acc[i][6] * asB.z + acc[i][7] * asB.w;
        float pd = acc[i][0] * adA.x + acc[i][1] * adA.y + acc[i][2] * adA.z + acc[i][3] * adA.w
                 + acc[i][4] * adB.x + acc[i][5] * adB.y + acc[i][6] * adB.z + acc[i][7] * adB.w;
        #pragma unroll
        for (int mask = 8; mask >= 1; mask >>= 1) {
            ps += __shfl_xor(ps, mask);
            pd += __shfl_xor(pd, mask);
        }
        if (r < n) {
            half4_t hlo, hhi;
            hlo.a = __floats2half2_rn(acc[i][0], acc[i][1]);
            hlo.b = __floats2half2_rn(acc[i][2], acc[i][3]);
            hhi.a = __floats2half2_rn(acc[i][4], acc[i][5]);
            hhi.b = __floats2half2_rn(acc[i][6], acc[i][7]);
            *(half4_t*)(H16 + (size_t)r * 128 + cg * 4)      = hlo;
            *(half4_t*)(H16 + (size_t)r * 128 + 64 + cg * 4) = hhi;
            if (cg == 0) { As[r] = ps; Ad[r] = pd; }
        }
    }
}

// ---------------- GAT aggregation: one wave per dst node (R10-verified) ----
// No segment-max: softmax is shift-invariant and logits are bounded (|e|<~15),
// so exp(e) cannot overflow fp32. Gather reads fp16 (4 B/lane/edge).
__global__ __launch_bounds__(256) void gat_agg_kernel(
    const __half* __restrict__ H16, const float* __restrict__ As, const float* __restrict__ Ad,
    const int* __restrict__ rowptr, const int* __restrict__ col,
    const float* __restrict__ bias, float* __restrict__ Out, int n, int relu)
{
    int wid = (blockIdx.x * blockDim.x + threadIdx.x) >> 6;
    int lane = threadIdx.x & 63;
    if (wid >= n) return;

    int beg = rowptr[wid], end = rowptr[wid + 1];
    int degn = end - beg;
    float adn = Ad[wid];

    int c0r = 0;
    if (lane < degn) c0r = col[beg + lane];

    float ex0 = 0.f;
    if (lane < degn) {
        float e = As[c0r] + adn;
        e = (e > 0.f) ? e : NEG_SLOPE * e;
        ex0 = __expf(e);
    }
    float den = ex0;
    for (int j = beg + lane + 64; j < end; j += 64) {
        float e = As[col[j]] + adn;
        e = (e > 0.f) ? e : NEG_SLOPE * e;
        den += __expf(e);
    }
    #pragma unroll
    for (int o = 32; o >= 1; o >>= 1) den += __shfl_xor(den, o);
    float inv = 1.f / den;

    const __half2* H2 = (const __half2*)H16;
    float accx = 0.f, accy = 0.f;
    int nfull = (degn < 64) ? degn : 64;
    int j = 0;
    for (; j + 8 <= nfull; j += 8) {
        int ss[8]; float ww[8]; __half2 hh[8];
        #pragma unroll
        for (int u = 0; u < 8; ++u) { ss[u] = __shfl(c0r, j + u); ww[u] = __shfl(ex0, j + u); }
        #pragma unroll
        for (int u = 0; u < 8; ++u) { hh[u] = H2[(size_t)ss[u] * 64 + lane]; }
        #pragma unroll
        for (int u = 0; u < 8; ++u) {
            float2 f = __half22float2(hh[u]);
            accx += ww[u] * f.x; accy += ww[u] * f.y;
        }
    }
    for (; j < nfull; ++j) {
        int s = __shfl(c0r, j);
        float w = __shfl(ex0, j);
        float2 f = __half22float2(H2[(size_t)s * 64 + lane]);
        accx += w * f.x; accy += w * f.y;
    }
    for (int jj = 64; jj < degn; ++jj) {
        int s = col[beg + jj];
        float e = As[s] + adn;
        e = (e > 0.f) ? e : NEG_SLOPE * e;
        float w = __expf(e);
        float2 f = __half22float2(H2[(size_t)s * 64 + lane]);
        accx += w * f.x; accy += w * f.y;
    }

    float2 b2 = ((const float2*)bias)[lane];
    float ox = accx * inv + b2.x;
    float oy = accy * inv + b2.y;
    if (relu) { ox = fmaxf(ox, 0.f); oy = fmaxf(oy, 0.f); }
    float2 o2; o2.x = ox; o2.y = oy;
    ((float2*)Out)[(size_t)wid * 64 + lane] = o2;
}

// ---------------- FC head: (M x 128) @ (128 x 57) + b ----------------
__global__ __launch_bounds__(256) void fc_kernel(
    const float* __restrict__ H, const float* __restrict__ Wf,
    const float* __restrict__ bf, float* __restrict__ Out, int n)
{
    __shared__ float Wl[128 * 64];       // 32 KB
    int tid = threadIdx.x;
    for (int i = tid; i < 128 * 64; i += 256) {
        int k = i >> 6, c = i & 63;
        Wl[i] = (c < 57) ? Wf[k * 57 + c] : 0.f;
    }
    __syncthreads();

    int cg = tid & 15, rg = tid >> 4;
    int c0 = cg * 4;
    int row0 = blockIdx.x * 32;
    int r0 = row0 + rg * 2, r1 = r0 + 1;
    int rc0 = (r0 < n) ? r0 : (n - 1);
    int rc1 = (r1 < n) ? r1 : (n - 1);

    float acc[2][4];
    #pragma unroll
    for (int i = 0; i < 2; ++i)
        #pragma unroll
        for (int c = 0; c < 4; ++c) acc[i][c] = 0.f;

    const float* X0 = H + (size_t)rc0 * 128;
    const float* X1 = H + (size_t)rc1 * 128;
    const float4* Wl4 = (const float4*)Wl;

    for (int k = 0; k < 128; k += 4) {
        float4 xa = *(const float4*)(X0 + k);
        float4 xb = *(const float4*)(X1 + k);
        #pragma unroll
        for (int kk = 0; kk < 4; ++kk) {
            float4 wv = Wl4[(k + kk) * 16 + cg];
            float x0s = (kk == 0) ? xa.x : (kk == 1) ? xa.y : (kk == 2) ? xa.z : xa.w;
            float x1s = (kk == 0) ? xb.x : (kk == 1) ? xb.y : (kk == 2) ? xb.z : xb.w;
            acc[0][0] += x0s * wv.x; acc[0][1] += x0s * wv.y;
            acc[0][2] += x0s * wv.z; acc[0][3] += x0s * wv.w;
            acc[1][0] += x1s * wv.x; acc[1][1] += x1s * wv.y;
            acc[1][2] += x1s * wv.z; acc[1][3] += x1s * wv.w;
        }
    }

    #pragma unroll
    for (int i = 0; i < 2; ++i) {
        int r = r0 + i;
        if (r >= n) continue;
        #pragma unroll
        for (int cc = 0; cc < 4; ++cc) {
            int c = c0 + cc;
            if (c < 57) Out[(size_t)r * 57 + c] = acc[i][cc] + bf[c];
        }
    }
}

// ---------------- launch ----------------

extern "C" void kernel_launch(void* const* d_in, const int* in_sizes, int n_in,
                              void* d_out, int out_size, void* d_ws, size_t ws_size,
                              hipStream_t stream)
{
    const float* x   = (const float*)d_in[0];
    const int*   ei  = (const int*)d_in[1];
    const float* W1  = (const float*)d_in[2];
    const float* a1s = (const float*)d_in[3];
    const float* a1d = (const float*)d_in[4];
    const float* b1  = (const float*)d_in[5];
    const float* W2  = (const float*)d_in[6];
    const float* a2s = (const float*)d_in[7];
    const float* a2d = (const float*)d_in[8];
    const float* b2  = (const float*)d_in[9];
    const float* fcw = (const float*)d_in[10];
    const float* fcb = (const float*)d_in[11];
    float* out = (float*)d_out;

    int n = in_sizes[0] / 128;
    int E = in_sizes[1] / 2;
    int tot = E + n;
    int nchunks = (n + 1023) / 1024;
    int quarter = (E + 3) >> 2;

    char* ws = (char*)d_ws;
    size_t off = 0;
    auto alloc = [&](size_t bytes) -> void* {
        void* p = ws + off;
        off += (bytes + 255) & ~(size_t)255;
        return p;
    };
    __half* h16   = (__half*)alloc((size_t)n * 128 * 2);   // gemm out (both layers)
    float* hF     = (float*)alloc((size_t)n * 128 * 4);    // agg out (both layers)
    float* As     = (float*)alloc((size_t)n * 4);
    float* Ad     = (float*)alloc((size_t)n * 4);
    int*   rowptr = (int*)alloc((size_t)(n + 1) * 4);
    int*   deg    = (int*)alloc((size_t)n * 4);
    int*   col    = (int*)alloc((size_t)tot * 4);
    int*   flag   = (int*)alloc(256);
    int*   csum   = (int*)alloc((size_t)64 * 4);

    hipMemsetAsync(deg, 0, (size_t)n * 4, stream);

    probe_i64_kernel<<<1, 64, 0, stream>>>(ei, E, flag);

    int gb = (n + 31) / 32;

    // gemm1 with fire-and-forget count prelude (atomics drain under compute)
    gemm1_count_kernel<<<gb, 256, 0, stream>>>(
        x, W1, a1s, a1d, h16, As, Ad, n, ei, E, flag, deg);

    scan1_kernel<<<nchunks, 1024, 0, stream>>>(deg, rowptr, csum, n);
    scan2_kernel<<<1, 64, 0, stream>>>(csum, nchunks);
    if (nchunks > 1)
        scan3_kernel<<<nchunks - 1, 1024, 0, stream>>>(csum, rowptr, n);

    int sb = (quarter + n + 255) / 256;
    scatter_kernel<<<sb, 256, 0, stream>>>(ei, E, n, flag, rowptr, deg, col);

    int ab = (n + 3) / 4;

    // layer 1 aggregation
    gat_agg_kernel<<<ab, 256, 0, stream>>>(h16, As, Ad, rowptr, col, b1, hF, n, 1);
    // layer 2
    gemm_h_kernel<<<gb, 256, 0, stream>>>(hF, W2, a2s, a2d, h16, As, Ad, n);
    gat_agg_kernel<<<ab, 256, 0, stream>>>(h16, As, Ad, rowptr, col, b2, hF, n, 0);
    // head
    fc_kernel<<<gb, 256, 0, stream>>>(hF, fcw, fcb, out, n);
}